// Round 4
// baseline (960.063 us; speedup 1.0000x reference)
//
#include <hip/hip_runtime.h>
#include <math.h>

#define NROWS 1048576
#define D 256
#define C 65
#define EPSV 1e-8f

typedef float f32x4 __attribute__((ext_vector_type(4)));

// --- Pre-kernel: weight norms -> d_ws (65 floats). One wave per cluster. ---
__global__ void wn_kernel(const float* __restrict__ w, float* __restrict__ wn) {
    int c = blockIdx.x;          // 0..64
    int l = threadIdx.x;         // 0..63
    float s = 0.f;
    #pragma unroll
    for (int d = l; d < D; d += 64) {
        float v = w[c * D + d];
        s = fmaf(v, v, s);
    }
    #pragma unroll
    for (int off = 32; off; off >>= 1) s += __shfl_down(s, off);
    if (l == 0) wn[c] = sqrtf(s);
}

// --- Main kernel: one thread per row; w staged in LDS (2 phases of [C][128]).
// Inner loop: broadcast ds_read_b128 + v_fmac, schedule pinned via
// sched_group_barrier (2 DS_READ, 8 VALU per cluster) to bound register
// pressure and keep acc[] in arch VGPRs (round-2 showed AGPR shuffling).
__global__ __launch_bounds__(256, 4) void scluster_kernel(
    const float* __restrict__ x, const float* __restrict__ w,
    const float* __restrict__ wn, float* __restrict__ out)
{
    __shared__ float wbuf[C * 128];          // 33,280 B (also reused as store-staging)
    const int tid = threadIdx.x;
    const int row = blockIdx.x * 256 + tid;
    const float* __restrict__ xr = x + (size_t)row * D;

    float acc[C];
    #pragma unroll
    for (int c = 0; c < C; ++c) acc[c] = 0.f;
    float xn2 = 0.f;

    #pragma unroll 1
    for (int p = 0; p < 2; ++p) {
        // stage w[:, p*128 .. p*128+127] -> wbuf[C][128]  (coalesced 16B)
        #pragma unroll 1
        for (int i = tid; i < C * 32; i += 256) {
            const int c  = i >> 5;
            const int j4 = (i & 31) << 2;
            *reinterpret_cast<f32x4*>(&wbuf[c * 128 + j4]) =
                *reinterpret_cast<const f32x4*>(&w[c * 256 + p * 128 + j4]);
        }
        __syncthreads();

        #pragma unroll 1
        for (int d0 = 0; d0 < 128; d0 += 8) {
            // x: stream-once -> nontemporal (keep w resident in L2)
            const f32x4 a = __builtin_nontemporal_load(
                reinterpret_cast<const f32x4*>(xr + p * 128 + d0));
            const f32x4 b = __builtin_nontemporal_load(
                reinterpret_cast<const f32x4*>(xr + p * 128 + d0 + 4));
            const float xv0 = a.x, xv1 = a.y, xv2 = a.z, xv3 = a.w;
            const float xv4 = b.x, xv5 = b.y, xv6 = b.z, xv7 = b.w;
            xn2 = fmaf(xv0, xv0, xn2); xn2 = fmaf(xv1, xv1, xn2);
            xn2 = fmaf(xv2, xv2, xn2); xn2 = fmaf(xv3, xv3, xn2);
            xn2 = fmaf(xv4, xv4, xn2); xn2 = fmaf(xv5, xv5, xn2);
            xn2 = fmaf(xv6, xv6, xn2); xn2 = fmaf(xv7, xv7, xn2);
            __builtin_amdgcn_sched_group_barrier(0x002, 8, 0);   // xn2 FMAs here
            #pragma unroll
            for (int c = 0; c < C; ++c) {
                const f32x4 w0 = *reinterpret_cast<const f32x4*>(&wbuf[c * 128 + d0]);
                const f32x4 w1 = *reinterpret_cast<const f32x4*>(&wbuf[c * 128 + d0 + 4]);
                float t = acc[c];
                t = fmaf(w0.x, xv0, t); t = fmaf(w0.y, xv1, t);
                t = fmaf(w0.z, xv2, t); t = fmaf(w0.w, xv3, t);
                t = fmaf(w1.x, xv4, t); t = fmaf(w1.y, xv5, t);
                t = fmaf(w1.z, xv6, t); t = fmaf(w1.w, xv7, t);
                acc[c] = t;
                // pin: 2 broadcast ds_reads then this cluster's 8 FMAs --
                // bounds ds_read hoisting so live set stays in arch VGPRs
                __builtin_amdgcn_sched_group_barrier(0x100, 2, 0); // DS_READ
                __builtin_amdgcn_sched_group_barrier(0x002, 8, 0); // VALU
            }
        }
        __syncthreads();   // before next-phase restage / store restage
    }

    // --- cosine sim + softmax, fully in registers ---
    const float xn = sqrtf(xn2);
    float m = -INFINITY;
    #pragma unroll
    for (int c = 0; c < C; ++c) {
        const float denom = fmaxf(xn * wn[c], EPSV);
        const float s = acc[c] * __builtin_amdgcn_rcpf(denom);
        acc[c] = s;
        m = fmaxf(m, s);
    }
    float sum = 0.f;
    #pragma unroll
    for (int c = 0; c < C; ++c) {
        const float e = __expf(acc[c] - m);
        acc[c] = e;
        sum += e;
    }
    const float rs = __builtin_amdgcn_rcpf(sum);
    #pragma unroll
    for (int c = 0; c < C; ++c) acc[c] *= rs;

    // --- coalesced store via LDS restage: waves {0,1} then {2,3} ---
    const int wv = tid >> 6;
    const int lane = tid & 63;
    float* obuf = wbuf;                      // [2][64*C] = 33,280 B, reused

    auto emit = [&](int slot) {
        float* tile = obuf + slot * (64 * C);
        // scatter own row into LDS: banks (lane*65+c)%32 = (lane+c)%32 -> 2/bank, free
        #pragma unroll
        for (int c = 0; c < C; ++c) tile[lane * C + c] = acc[c];
        asm volatile("s_waitcnt lgkmcnt(0)" ::: "memory");  // same-wave write->read order
        const size_t gbase = ((size_t)blockIdx.x * 256 + (size_t)wv * 64) * C;
        // 64*65 = 4160 dwords: 16 float4/lane + 1 dword/lane, all 16B-aligned
        #pragma unroll
        for (int k = 0; k < 16; ++k) {
            const f32x4 v = *reinterpret_cast<const f32x4*>(&tile[k * 256 + lane * 4]);
            __builtin_nontemporal_store(v,
                reinterpret_cast<f32x4*>(&out[gbase + k * 256 + lane * 4]));
        }
        __builtin_nontemporal_store(tile[4096 + lane], &out[gbase + 4096 + lane]);
    };

    if (wv < 2) emit(wv);          // waves 0,1 use the two LDS slots
    __syncthreads();
    if (wv >= 2) emit(wv - 2);     // then waves 2,3
}

extern "C" void kernel_launch(void* const* d_in, const int* in_sizes, int n_in,
                              void* d_out, int out_size, void* d_ws, size_t ws_size,
                              hipStream_t stream) {
    const float* x = (const float*)d_in[0];
    const float* w = (const float*)d_in[1];
    float* out = (float*)d_out;
    float* wn = (float*)d_ws;

    wn_kernel<<<C, 64, 0, stream>>>(w, wn);
    scluster_kernel<<<NROWS / 256, 256, 0, stream>>>(x, w, wn, out);
}

// Round 5
// 517.263 us; speedup vs baseline: 1.8560x; 1.8560x over previous
//
#include <hip/hip_runtime.h>
#include <hip/hip_bf16.h>
#include <math.h>

#define NROWS 1048576
#define D 256
#define C 65
#define MT 5                 // cluster tiles of 16 (80 cols, 65..79 zero-pad)
#define KS 8                 // k-steps of 32 (K=256)
#define TILES_PER_WAVE 8
#define TILES_PER_BLOCK 32   // 4 waves * 8 -> 512 rows/block, grid 2048

typedef float f32x4  __attribute__((ext_vector_type(4)));
typedef float f32x4u __attribute__((ext_vector_type(4), aligned(4)));  // out rows are 260B -> x4 stores only 4B-aligned
typedef short bf16x8 __attribute__((ext_vector_type(8)));

__device__ __forceinline__ short f2bf(float f) {
    __hip_bfloat16 h = __float2bfloat16(f);   // RNE hw cvt
    return *reinterpret_cast<short*>(&h);
}

// --- Pre-kernel: weight norms -> d_ws (65 floats). One wave per cluster. ---
__global__ void wn_kernel(const float* __restrict__ w, float* __restrict__ wn) {
    int c = blockIdx.x;
    int l = threadIdx.x;
    float s = 0.f;
    #pragma unroll
    for (int d = l; d < D; d += 64) {
        float v = w[c * D + d];
        s = fmaf(v, v, s);
    }
    #pragma unroll
    for (int off = 32; off; off >>= 1) s += __shfl_down(s, off);
    if (l == 0) wn[c] = sqrtf(s);
}

// --- Main kernel: bf16 MFMA. D[cluster][xrow] = (w/wn) . x  (sim*xn), then
// per-lane softmax epilogue (each lane owns one x-row) and direct f32x4 stores.
__global__ __launch_bounds__(256, 4) void scluster_mfma(
    const float* __restrict__ x, const float* __restrict__ w,
    const float* __restrict__ wn, float* __restrict__ out)
{
    __shared__ bf16x8 wfrag[MT * KS * 64];   // 40KB prepacked, prenormalized A-frags

    const int tid = threadIdx.x;

    // ---- stage A-fragments: frag f=(m,ks,lane): w_hat[m*16+(lane&15)][ks*32+(lane>>4)*8+j]
    #pragma unroll 1
    for (int f = tid; f < MT * KS * 64; f += 256) {
        const int m  = f >> 9;
        const int ks = (f >> 6) & 7;
        const int l  = f & 63;
        const int c    = m * 16 + (l & 15);
        const int koff = ks * 32 + (l >> 4) * 8;
        bf16x8 fr;
        if (c < C) {
            const float inv = __builtin_amdgcn_rcpf(wn[c]);
            const f32x4 a = *reinterpret_cast<const f32x4*>(&w[c * D + koff]);
            const f32x4 b = *reinterpret_cast<const f32x4*>(&w[c * D + koff + 4]);
            fr[0] = f2bf(a.x * inv); fr[1] = f2bf(a.y * inv);
            fr[2] = f2bf(a.z * inv); fr[3] = f2bf(a.w * inv);
            fr[4] = f2bf(b.x * inv); fr[5] = f2bf(b.y * inv);
            fr[6] = f2bf(b.z * inv); fr[7] = f2bf(b.w * inv);
        } else {
            #pragma unroll
            for (int j = 0; j < 8; ++j) fr[j] = 0;
        }
        wfrag[f] = fr;
    }
    __syncthreads();

    const int wv   = tid >> 6;
    const int l    = tid & 63;
    const int g    = l >> 4;     // k-group within fragment
    const int jrow = l & 15;     // this lane's x-row (D's col) -- owns it end-to-end

    #pragma unroll 1
    for (int it = 0; it < TILES_PER_WAVE; ++it) {
        const int tile = blockIdx.x * TILES_PER_BLOCK + wv * TILES_PER_WAVE + it;
        const size_t row = (size_t)tile * 16 + jrow;
        const float* __restrict__ xp = x + row * D + g * 8;

        f32x4 acc[MT];
        #pragma unroll
        for (int m = 0; m < MT; ++m) acc[m] = f32x4{0.f, 0.f, 0.f, 0.f};
        float xn2 = 0.f;

        #pragma unroll
        for (int ks = 0; ks < KS; ++ks) {
            const f32x4 a = *reinterpret_cast<const f32x4*>(xp + ks * 32);
            const f32x4 b = *reinterpret_cast<const f32x4*>(xp + ks * 32 + 4);
            xn2 = fmaf(a.x, a.x, xn2); xn2 = fmaf(a.y, a.y, xn2);
            xn2 = fmaf(a.z, a.z, xn2); xn2 = fmaf(a.w, a.w, xn2);
            xn2 = fmaf(b.x, b.x, xn2); xn2 = fmaf(b.y, b.y, xn2);
            xn2 = fmaf(b.z, b.z, xn2); xn2 = fmaf(b.w, b.w, xn2);
            bf16x8 xf;
            xf[0] = f2bf(a.x); xf[1] = f2bf(a.y); xf[2] = f2bf(a.z); xf[3] = f2bf(a.w);
            xf[4] = f2bf(b.x); xf[5] = f2bf(b.y); xf[6] = f2bf(b.z); xf[7] = f2bf(b.w);
            #pragma unroll
            for (int m = 0; m < MT; ++m)
                acc[m] = __builtin_amdgcn_mfma_f32_16x16x32_bf16(
                    wfrag[(m * KS + ks) * 64 + l], xf, acc[m], 0, 0, 0);
        }

        // full ||x_row||^2: partials live in the 4 lanes {jrow, +16, +32, +48}
        xn2 += __shfl_xor(xn2, 16);
        xn2 += __shfl_xor(xn2, 32);
        const float rxn = __builtin_amdgcn_rcpf(sqrtf(xn2));

        // sim = dot_norm / xn ; this lane holds clusters c = m*16 + 4*g + r
        f32x4 sv[MT];
        float mx = -INFINITY;
        #pragma unroll
        for (int m = 0; m < MT; ++m) {
            #pragma unroll
            for (int r = 0; r < 4; ++r) {
                float v = acc[m][r] * rxn;
                if (m == 4 && !(r == 0)) v = -1e30f;          // pads (c>64)
                if (m == 4 && r == 0 && g != 0) v = -1e30f;   // c=64 only at g==0
                sv[m][r] = v;
                mx = fmaxf(mx, v);
            }
        }
        mx = fmaxf(mx, __shfl_xor(mx, 16));
        mx = fmaxf(mx, __shfl_xor(mx, 32));

        float sum = 0.f;
        #pragma unroll
        for (int m = 0; m < MT; ++m) {
            #pragma unroll
            for (int r = 0; r < 4; ++r) {
                const float e = __expf(sv[m][r] - mx);        // pads underflow to 0
                sv[m][r] = e;
                sum += e;
            }
        }
        sum += __shfl_xor(sum, 16);
        sum += __shfl_xor(sum, 32);
        const float rs = __builtin_amdgcn_rcpf(sum);

        // stores: per m<4, wave writes 16 rows x 64B contiguous chunks
        float* __restrict__ op = out + row * C;
        #pragma unroll
        for (int m = 0; m < 4; ++m) {
            const f32x4 v = sv[m] * rs;
            __builtin_nontemporal_store(__builtin_bit_cast(f32x4u, v),
                reinterpret_cast<f32x4u*>(op + m * 16 + 4 * g));
        }
        if (g == 0) __builtin_nontemporal_store(sv[4][0] * rs, op + 64);
    }
}

extern "C" void kernel_launch(void* const* d_in, const int* in_sizes, int n_in,
                              void* d_out, int out_size, void* d_ws, size_t ws_size,
                              hipStream_t stream) {
    const float* x = (const float*)d_in[0];
    const float* w = (const float*)d_in[1];
    float* out = (float*)d_out;
    float* wn = (float*)d_ws;

    wn_kernel<<<C, 64, 0, stream>>>(w, wn);
    scluster_mfma<<<NROWS / 16 / TILES_PER_BLOCK, 256, 0, stream>>>(x, w, wn, out);
}

// Round 6
// 452.114 us; speedup vs baseline: 2.1235x; 1.1441x over previous
//
#include <hip/hip_runtime.h>
#include <hip/hip_bf16.h>
#include <math.h>

#define NROWS 1048576
#define D 256
#define C 65
#define MT 5                 // cluster tiles of 16 (80 cols, 65..79 zero-pad)
#define KS 8                 // k-steps of 32 (K=256)
#define TILES_PER_WAVE 8
#define TILES_PER_BLOCK 32   // 4 waves * 8 -> 512 rows/block, grid 2048

typedef float f32x4  __attribute__((ext_vector_type(4)));
typedef float f32x4u __attribute__((ext_vector_type(4), aligned(4)));
typedef short bf16x8 __attribute__((ext_vector_type(8)));

__device__ __forceinline__ short f2bf(float f) {
    __hip_bfloat16 h = __float2bfloat16(f);   // RNE hw cvt
    return *reinterpret_cast<short*>(&h);
}

// --- Pre-kernel: weight norms -> d_ws (65 floats). One wave per cluster. ---
__global__ void wn_kernel(const float* __restrict__ w, float* __restrict__ wn) {
    int c = blockIdx.x;
    int l = threadIdx.x;
    float s = 0.f;
    #pragma unroll
    for (int d = l; d < D; d += 64) {
        float v = w[c * D + d];
        s = fmaf(v, v, s);
    }
    #pragma unroll
    for (int off = 32; off; off >>= 1) s += __shfl_down(s, off);
    if (l == 0) wn[c] = sqrtf(s);
}

// --- Main kernel: bf16 MFMA, software-pipelined half-tile x prefetch.
// Per tile: {wait+cvt half0 | issue half1 | MFMA ks0..3 | wait+cvt half1 |
// issue half0(next) | MFMA ks4..7 | softmax epilogue + stores}.
__global__ __launch_bounds__(256, 4) void scluster_mfma(
    const float* __restrict__ x, const float* __restrict__ w,
    const float* __restrict__ wn, float* __restrict__ out)
{
    __shared__ bf16x8 wfrag[MT * KS * 64];   // 40KB prepacked, prenormalized A-frags

    const int tid = threadIdx.x;

    // ---- stage A-fragments: f=(m,ks,lane): w_hat[m*16+(lane&15)][ks*32+(lane>>4)*8+j]
    #pragma unroll 1
    for (int f = tid; f < MT * KS * 64; f += 256) {
        const int m  = f >> 9;
        const int ks = (f >> 6) & 7;
        const int l  = f & 63;
        const int c    = m * 16 + (l & 15);
        const int koff = ks * 32 + (l >> 4) * 8;
        bf16x8 fr;
        if (c < C) {
            const float inv = __builtin_amdgcn_rcpf(wn[c]);
            const f32x4 a = *reinterpret_cast<const f32x4*>(&w[c * D + koff]);
            const f32x4 b = *reinterpret_cast<const f32x4*>(&w[c * D + koff + 4]);
            fr[0] = f2bf(a.x * inv); fr[1] = f2bf(a.y * inv);
            fr[2] = f2bf(a.z * inv); fr[3] = f2bf(a.w * inv);
            fr[4] = f2bf(b.x * inv); fr[5] = f2bf(b.y * inv);
            fr[6] = f2bf(b.z * inv); fr[7] = f2bf(b.w * inv);
        } else {
            #pragma unroll
            for (int j = 0; j < 8; ++j) fr[j] = 0;
        }
        wfrag[f] = fr;
    }
    __syncthreads();

    const int wv   = tid >> 6;
    const int l    = tid & 63;
    const int g    = l >> 4;     // k-group within fragment
    const int jrow = l & 15;     // this lane's x-row; owned end-to-end

    const size_t row0 = (size_t)(blockIdx.x * TILES_PER_BLOCK + wv * TILES_PER_WAVE) * 16 + jrow;
    const float* __restrict__ xp0 = x + row0 * D + g * 8;

    f32x4 p[8];                  // rolling half-tile load buffer (32 VGPR)
    // prologue: half0 of tile 0
    #pragma unroll
    for (int k = 0; k < 4; ++k) {
        p[2 * k]     = *reinterpret_cast<const f32x4*>(xp0 + k * 32);
        p[2 * k + 1] = *reinterpret_cast<const f32x4*>(xp0 + k * 32 + 4);
    }

    #pragma unroll 1
    for (int it = 0; it < TILES_PER_WAVE; ++it) {
        const float* __restrict__ xp = xp0 + (size_t)it * 16 * D;        // this tile
        const float* __restrict__ xq = xp0 + (size_t)(it + 1) * 16 * D;  // next tile

        f32x4 acc[MT];
        #pragma unroll
        for (int m = 0; m < MT; ++m) acc[m] = f32x4{0.f, 0.f, 0.f, 0.f};
        float xn2 = 0.f;

        bf16x8 xfA[4], xfB[4];

        // ---- consume half0 (waits vmcnt), convert, accumulate xn2
        #pragma unroll
        for (int k = 0; k < 4; ++k) {
            const f32x4 a = p[2 * k], b = p[2 * k + 1];
            xn2 = fmaf(a.x, a.x, xn2); xn2 = fmaf(a.y, a.y, xn2);
            xn2 = fmaf(a.z, a.z, xn2); xn2 = fmaf(a.w, a.w, xn2);
            xn2 = fmaf(b.x, b.x, xn2); xn2 = fmaf(b.y, b.y, xn2);
            xn2 = fmaf(b.z, b.z, xn2); xn2 = fmaf(b.w, b.w, xn2);
            bf16x8 xf;
            xf[0] = f2bf(a.x); xf[1] = f2bf(a.y); xf[2] = f2bf(a.z); xf[3] = f2bf(a.w);
            xf[4] = f2bf(b.x); xf[5] = f2bf(b.y); xf[6] = f2bf(b.z); xf[7] = f2bf(b.w);
            xfA[k] = xf;
        }
        // ---- issue half1 loads NOW (hidden under MFMA phase A)
        #pragma unroll
        for (int k = 0; k < 4; ++k) {
            p[2 * k]     = *reinterpret_cast<const f32x4*>(xp + 128 + k * 32);
            p[2 * k + 1] = *reinterpret_cast<const f32x4*>(xp + 128 + k * 32 + 4);
        }
        __builtin_amdgcn_sched_barrier(0);   // loads must issue before MFMA phase
        // ---- MFMA phase A: ks = 0..3
        #pragma unroll
        for (int ks = 0; ks < 4; ++ks)
            #pragma unroll
            for (int m = 0; m < MT; ++m)
                acc[m] = __builtin_amdgcn_mfma_f32_16x16x32_bf16(
                    wfrag[(m * KS + ks) * 64 + l], xfA[ks], acc[m], 0, 0, 0);

        // ---- consume half1, convert
        #pragma unroll
        for (int k = 0; k < 4; ++k) {
            const f32x4 a = p[2 * k], b = p[2 * k + 1];
            xn2 = fmaf(a.x, a.x, xn2); xn2 = fmaf(a.y, a.y, xn2);
            xn2 = fmaf(a.z, a.z, xn2); xn2 = fmaf(a.w, a.w, xn2);
            xn2 = fmaf(b.x, b.x, xn2); xn2 = fmaf(b.y, b.y, xn2);
            xn2 = fmaf(b.z, b.z, xn2); xn2 = fmaf(b.w, b.w, xn2);
            bf16x8 xf;
            xf[0] = f2bf(a.x); xf[1] = f2bf(a.y); xf[2] = f2bf(a.z); xf[3] = f2bf(a.w);
            xf[4] = f2bf(b.x); xf[5] = f2bf(b.y); xf[6] = f2bf(b.z); xf[7] = f2bf(b.w);
            xfB[k] = xf;
        }
        // ---- issue half0 of NEXT tile (hidden under MFMA phase B + epilogue)
        if (it < TILES_PER_WAVE - 1) {
            #pragma unroll
            for (int k = 0; k < 4; ++k) {
                p[2 * k]     = *reinterpret_cast<const f32x4*>(xq + k * 32);
                p[2 * k + 1] = *reinterpret_cast<const f32x4*>(xq + k * 32 + 4);
            }
        }
        __builtin_amdgcn_sched_barrier(0);
        // ---- MFMA phase B: ks = 4..7
        #pragma unroll
        for (int ks = 0; ks < 4; ++ks)
            #pragma unroll
            for (int m = 0; m < MT; ++m)
                acc[m] = __builtin_amdgcn_mfma_f32_16x16x32_bf16(
                    wfrag[(m * KS + ks + 4) * 64 + l], xfB[ks], acc[m], 0, 0, 0);

        // ---- epilogue: xn reduce, softmax over this lane's 20 clusters (in acc)
        xn2 += __shfl_xor(xn2, 16);
        xn2 += __shfl_xor(xn2, 32);
        const float rxn = __builtin_amdgcn_rcpf(sqrtf(xn2));

        float mx = -INFINITY;
        #pragma unroll
        for (int m = 0; m < MT; ++m) {
            #pragma unroll
            for (int r = 0; r < 4; ++r) {
                float v = acc[m][r] * rxn;
                if (m == 4 && !(r == 0)) v = -1e30f;          // pads (c>64)
                if (m == 4 && r == 0 && g != 0) v = -1e30f;   // c=64 only at g==0
                acc[m][r] = v;
                mx = fmaxf(mx, v);
            }
        }
        mx = fmaxf(mx, __shfl_xor(mx, 16));
        mx = fmaxf(mx, __shfl_xor(mx, 32));

        float sum = 0.f;
        #pragma unroll
        for (int m = 0; m < MT; ++m) {
            #pragma unroll
            for (int r = 0; r < 4; ++r) {
                const float e = __expf(acc[m][r] - mx);       // pads underflow to 0
                acc[m][r] = e;
                sum += e;
            }
        }
        sum += __shfl_xor(sum, 16);
        sum += __shfl_xor(sum, 32);
        const float rs = __builtin_amdgcn_rcpf(sum);

        const size_t row = row0 + (size_t)it * 16;
        float* __restrict__ op = out + row * C;
        #pragma unroll
        for (int m = 0; m < 4; ++m) {
            const f32x4 v = acc[m] * rs;
            __builtin_nontemporal_store(__builtin_bit_cast(f32x4u, v),
                reinterpret_cast<f32x4u*>(op + m * 16 + 4 * g));
        }
        if (g == 0) __builtin_nontemporal_store(acc[4][0] * rs, op + 64);
    }
}

extern "C" void kernel_launch(void* const* d_in, const int* in_sizes, int n_in,
                              void* d_out, int out_size, void* d_ws, size_t ws_size,
                              hipStream_t stream) {
    const float* x = (const float*)d_in[0];
    const float* w = (const float*)d_in[1];
    float* out = (float*)d_out;
    float* wn = (float*)d_ws;

    wn_kernel<<<C, 64, 0, stream>>>(w, wn);
    scluster_mfma<<<NROWS / 16 / TILES_PER_BLOCK, 256, 0, stream>>>(x, w, wn, out);
}

// Round 7
// 271.786 us; speedup vs baseline: 3.5324x; 1.6635x over previous
//
#include <hip/hip_runtime.h>
#include <hip/hip_bf16.h>
#include <math.h>

#define NROWS 1048576
#define D 256
#define C 65
#define MT 4                 // cluster tiles of 16 -> c 0..63 via MFMA; c=64 via VALU
#define KS 8                 // k-steps of 32 (K=256)
#define TILES_PER_WAVE 8
#define TILES_PER_BLOCK 32   // 4 waves * 8 -> 512 rows/block, grid 2048

typedef float f32x4  __attribute__((ext_vector_type(4)));
typedef short bf16x8 __attribute__((ext_vector_type(8)));

__device__ __forceinline__ short f2bf(float f) {
    __hip_bfloat16 h = __float2bfloat16(f);   // RNE hw cvt
    return *reinterpret_cast<short*>(&h);
}

// --- Pre-kernel: weight norms -> d_ws (65 floats). One wave per cluster. ---
__global__ void wn_kernel(const float* __restrict__ w, float* __restrict__ wn) {
    int c = blockIdx.x;
    int l = threadIdx.x;
    float s = 0.f;
    #pragma unroll
    for (int d = l; d < D; d += 64) {
        float v = w[c * D + d];
        s = fmaf(v, v, s);
    }
    #pragma unroll
    for (int off = 32; off; off >>= 1) s += __shfl_down(s, off);
    if (l == 0) wn[c] = sqrtf(s);
}

// --- Main kernel: bf16 MFMA (c<64) + VALU dot (c=64), pipelined x prefetch,
// softmax in-register, output restaged through LDS for full-line stores.
__global__ __launch_bounds__(256, 4) void scluster_mfma(
    const float* __restrict__ x, const float* __restrict__ w,
    const float* __restrict__ wn, float* __restrict__ out)
{
    __shared__ bf16x8 wfrag[MT * KS * 64];   // 32KB prepacked, prenormalized A-frags
    __shared__ float  wb64[D];               // 1KB: w_hat[64][*] in f32
    __shared__ float  obuf[4][16 * C];       // 16.6KB per-wave store staging

    const int tid = threadIdx.x;

    // ---- stage A-fragments: f=(m,ks,lane): w_hat[m*16+(lane&15)][ks*32+(lane>>4)*8+j]
    #pragma unroll 1
    for (int f = tid; f < MT * KS * 64; f += 256) {
        const int m  = f >> 9;
        const int ks = (f >> 6) & 7;
        const int l  = f & 63;
        const int c    = m * 16 + (l & 15);
        const int koff = ks * 32 + (l >> 4) * 8;
        const float inv = __builtin_amdgcn_rcpf(wn[c]);
        const f32x4 a = *reinterpret_cast<const f32x4*>(&w[c * D + koff]);
        const f32x4 b = *reinterpret_cast<const f32x4*>(&w[c * D + koff + 4]);
        bf16x8 fr;
        fr[0] = f2bf(a.x * inv); fr[1] = f2bf(a.y * inv);
        fr[2] = f2bf(a.z * inv); fr[3] = f2bf(a.w * inv);
        fr[4] = f2bf(b.x * inv); fr[5] = f2bf(b.y * inv);
        fr[6] = f2bf(b.z * inv); fr[7] = f2bf(b.w * inv);
        wfrag[f] = fr;
    }
    if (tid < 64) {
        const float inv = __builtin_amdgcn_rcpf(wn[64]);
        const f32x4 a = *reinterpret_cast<const f32x4*>(&w[64 * D + tid * 4]);
        f32x4 v; v.x = a.x * inv; v.y = a.y * inv; v.z = a.z * inv; v.w = a.w * inv;
        *reinterpret_cast<f32x4*>(&wb64[tid * 4]) = v;
    }
    __syncthreads();

    const int wv   = tid >> 6;
    const int l    = tid & 63;
    const int g    = l >> 4;     // k-group within fragment
    const int jrow = l & 15;     // this lane's x-row; owned end-to-end

    const int   tile0 = blockIdx.x * TILES_PER_BLOCK + wv * TILES_PER_WAVE;
    const size_t row0 = (size_t)tile0 * 16 + jrow;
    const float* __restrict__ xp0 = x + row0 * D + g * 8;
    float* const tb = obuf[wv];

    f32x4 p[8];                  // rolling half-tile load buffer (32 VGPR)
    #pragma unroll
    for (int k = 0; k < 4; ++k) {
        p[2 * k]     = *reinterpret_cast<const f32x4*>(xp0 + k * 32);
        p[2 * k + 1] = *reinterpret_cast<const f32x4*>(xp0 + k * 32 + 4);
    }

    #pragma unroll 1
    for (int it = 0; it < TILES_PER_WAVE; ++it) {
        const float* __restrict__ xp = xp0 + (size_t)it * 16 * D;        // this tile
        const float* __restrict__ xq = xp0 + (size_t)(it + 1) * 16 * D;  // next tile

        f32x4 acc[MT];
        #pragma unroll
        for (int m = 0; m < MT; ++m) acc[m] = f32x4{0.f, 0.f, 0.f, 0.f};
        float xn2 = 0.f, acc64 = 0.f;

        bf16x8 xfA[4], xfB[4];

        // ---- consume half0 (waits vmcnt), cvt + xn2 + c64 partial
        #pragma unroll
        for (int k = 0; k < 4; ++k) {
            const f32x4 a = p[2 * k], b = p[2 * k + 1];
            xn2 = fmaf(a.x, a.x, xn2); xn2 = fmaf(a.y, a.y, xn2);
            xn2 = fmaf(a.z, a.z, xn2); xn2 = fmaf(a.w, a.w, xn2);
            xn2 = fmaf(b.x, b.x, xn2); xn2 = fmaf(b.y, b.y, xn2);
            xn2 = fmaf(b.z, b.z, xn2); xn2 = fmaf(b.w, b.w, xn2);
            const f32x4 wa = *reinterpret_cast<const f32x4*>(&wb64[g * 8 + k * 32]);
            const f32x4 wb = *reinterpret_cast<const f32x4*>(&wb64[g * 8 + k * 32 + 4]);
            acc64 = fmaf(wa.x, a.x, acc64); acc64 = fmaf(wa.y, a.y, acc64);
            acc64 = fmaf(wa.z, a.z, acc64); acc64 = fmaf(wa.w, a.w, acc64);
            acc64 = fmaf(wb.x, b.x, acc64); acc64 = fmaf(wb.y, b.y, acc64);
            acc64 = fmaf(wb.z, b.z, acc64); acc64 = fmaf(wb.w, b.w, acc64);
            bf16x8 xf;
            xf[0] = f2bf(a.x); xf[1] = f2bf(a.y); xf[2] = f2bf(a.z); xf[3] = f2bf(a.w);
            xf[4] = f2bf(b.x); xf[5] = f2bf(b.y); xf[6] = f2bf(b.z); xf[7] = f2bf(b.w);
            xfA[k] = xf;
        }
        // ---- issue half1 loads NOW (hidden under MFMA phase A)
        #pragma unroll
        for (int k = 0; k < 4; ++k) {
            p[2 * k]     = *reinterpret_cast<const f32x4*>(xp + 128 + k * 32);
            p[2 * k + 1] = *reinterpret_cast<const f32x4*>(xp + 128 + k * 32 + 4);
        }
        __builtin_amdgcn_sched_barrier(0);
        // ---- MFMA phase A: ks = 0..3
        #pragma unroll
        for (int ks = 0; ks < 4; ++ks)
            #pragma unroll
            for (int m = 0; m < MT; ++m)
                acc[m] = __builtin_amdgcn_mfma_f32_16x16x32_bf16(
                    wfrag[(m * KS + ks) * 64 + l], xfA[ks], acc[m], 0, 0, 0);

        // ---- consume half1
        #pragma unroll
        for (int k = 0; k < 4; ++k) {
            const f32x4 a = p[2 * k], b = p[2 * k + 1];
            xn2 = fmaf(a.x, a.x, xn2); xn2 = fmaf(a.y, a.y, xn2);
            xn2 = fmaf(a.z, a.z, xn2); xn2 = fmaf(a.w, a.w, xn2);
            xn2 = fmaf(b.x, b.x, xn2); xn2 = fmaf(b.y, b.y, xn2);
            xn2 = fmaf(b.z, b.z, xn2); xn2 = fmaf(b.w, b.w, xn2);
            const f32x4 wa = *reinterpret_cast<const f32x4*>(&wb64[g * 8 + (k + 4) * 32]);
            const f32x4 wb = *reinterpret_cast<const f32x4*>(&wb64[g * 8 + (k + 4) * 32 + 4]);
            acc64 = fmaf(wa.x, a.x, acc64); acc64 = fmaf(wa.y, a.y, acc64);
            acc64 = fmaf(wa.z, a.z, acc64); acc64 = fmaf(wa.w, a.w, acc64);
            acc64 = fmaf(wb.x, b.x, acc64); acc64 = fmaf(wb.y, b.y, acc64);
            acc64 = fmaf(wb.z, b.z, acc64); acc64 = fmaf(wb.w, b.w, acc64);
            bf16x8 xf;
            xf[0] = f2bf(a.x); xf[1] = f2bf(a.y); xf[2] = f2bf(a.z); xf[3] = f2bf(a.w);
            xf[4] = f2bf(b.x); xf[5] = f2bf(b.y); xf[6] = f2bf(b.z); xf[7] = f2bf(b.w);
            xfB[k] = xf;
        }
        // ---- issue half0 of NEXT tile (hidden under MFMA phase B + epilogue)
        if (it < TILES_PER_WAVE - 1) {
            #pragma unroll
            for (int k = 0; k < 4; ++k) {
                p[2 * k]     = *reinterpret_cast<const f32x4*>(xq + k * 32);
                p[2 * k + 1] = *reinterpret_cast<const f32x4*>(xq + k * 32 + 4);
            }
        }
        __builtin_amdgcn_sched_barrier(0);
        // ---- MFMA phase B: ks = 4..7
        #pragma unroll
        for (int ks = 0; ks < 4; ++ks)
            #pragma unroll
            for (int m = 0; m < MT; ++m)
                acc[m] = __builtin_amdgcn_mfma_f32_16x16x32_bf16(
                    wfrag[(m * KS + ks + 4) * 64 + l], xfB[ks], acc[m], 0, 0, 0);

        // ---- epilogue: reduces, softmax, LDS restage, full-line stores
        xn2   += __shfl_xor(xn2, 16);   xn2   += __shfl_xor(xn2, 32);
        acc64 += __shfl_xor(acc64, 16); acc64 += __shfl_xor(acc64, 32);
        const float rxn = __builtin_amdgcn_rcpf(sqrtf(xn2));
        const float s64 = acc64 * rxn;

        float mx = s64;
        #pragma unroll
        for (int m = 0; m < MT; ++m) {
            #pragma unroll
            for (int r = 0; r < 4; ++r) {
                const float v = acc[m][r] * rxn;
                acc[m][r] = v;
                mx = fmaxf(mx, v);
            }
        }
        mx = fmaxf(mx, __shfl_xor(mx, 16));
        mx = fmaxf(mx, __shfl_xor(mx, 32));

        const float e64 = __expf(s64 - mx);
        float sum = (g == 0) ? e64 : 0.f;
        #pragma unroll
        for (int m = 0; m < MT; ++m) {
            #pragma unroll
            for (int r = 0; r < 4; ++r) {
                const float e = __expf(acc[m][r] - mx);
                acc[m][r] = e;
                sum += e;
            }
        }
        sum += __shfl_xor(sum, 16);
        sum += __shfl_xor(sum, 32);
        const float rs = __builtin_amdgcn_rcpf(sum);

        // scatter this wave's 16x65 tile into LDS (banks (jrow+c)%32, <=4-way)
        #pragma unroll
        for (int m = 0; m < MT; ++m) {
            #pragma unroll
            for (int r = 0; r < 4; ++r)
                tb[jrow * C + m * 16 + g * 4 + r] = acc[m][r] * rs;
        }
        if (g == 0) tb[jrow * C + 64] = e64 * rs;
        asm volatile("s_waitcnt lgkmcnt(0)" ::: "memory");  // same-wave ds order

        // 16*65 floats = 4160B = 65 full lines; aligned f32x4 coalesced NT stores
        const size_t gb = (size_t)(tile0 + it) * 16 * C;
        #pragma unroll
        for (int rd = 0; rd < 4; ++rd) {
            const int idx = rd * 64 + l;
            const f32x4 v = *reinterpret_cast<const f32x4*>(&tb[idx * 4]);
            __builtin_nontemporal_store(v, reinterpret_cast<f32x4*>(&out[gb + idx * 4]));
        }
        if (l < 4) {
            const int idx = 256 + l;
            const f32x4 v = *reinterpret_cast<const f32x4*>(&tb[idx * 4]);
            __builtin_nontemporal_store(v, reinterpret_cast<f32x4*>(&out[gb + idx * 4]));
        }
    }
}

extern "C" void kernel_launch(void* const* d_in, const int* in_sizes, int n_in,
                              void* d_out, int out_size, void* d_ws, size_t ws_size,
                              hipStream_t stream) {
    const float* x = (const float*)d_in[0];
    const float* w = (const float*)d_in[1];
    float* out = (float*)d_out;
    float* wn = (float*)d_ws;

    wn_kernel<<<C, 64, 0, stream>>>(w, wn);
    scluster_mfma<<<NROWS / 16 / TILES_PER_BLOCK, 256, 0, stream>>>(x, w, wn, out);
}